// Round 8
// baseline (285.611 us; speedup 1.0000x reference)
//
#include <hip/hip_runtime.h>
#include <hip/hip_fp16.h>
#include <math.h>

#define NN 100000
#define NE 1600000
#define KF 48
#define NEDGE_ALL (2 * NE)

#define BKT_NODES 128                    // nodes per bucket (dst >> 7)
#define NBKT_PER  782                    // ceil(100000/128)
#define NBKT      1564                   // pos buckets then neg buckets
#define PACK_EPB  8192                   // edges per pack block (private region size)
#define NPACK_BLOCKS 391                 // ceil(3.2M / 8192)
#define OT_STRIDE 392                    // offT row stride (>= NPACK_BLOCKS)
#define CAP2      2432                   // per-bucket srt capacity (mean 2046 + >8 sigma)

typedef _Float16 half2v __attribute__((ext_vector_type(2)));
typedef _Float16 half4v __attribute__((ext_vector_type(4)));

#if defined(__has_builtin)
#if __has_builtin(__builtin_amdgcn_fdot2)
#define HAVE_FDOT2 1
#endif
#endif

__device__ __forceinline__ void acc_pair(float& ax, float& ay, half2v v)
{
#ifdef HAVE_FDOT2
    ax = __builtin_amdgcn_fdot2(v, (half2v){(_Float16)1.f, (_Float16)0.f}, ax, false);
    ay = __builtin_amdgcn_fdot2(v, (half2v){(_Float16)0.f, (_Float16)1.f}, ay, false);
#else
    ax += (float)v.x;
    ay += (float)v.y;
#endif
}

// ---------------- phase 1: fused cvt + atomic-free block-private pack ----------------
__global__ __launch_bounds__(1024) void pack_kernel(
    const float* __restrict__ x,
    const int* __restrict__ ei_pos,
    const int* __restrict__ ei_neg,
    unsigned short* __restrict__ offT,   // [(NBKT+1) * OT_STRIDE]
    unsigned* __restrict__ plist,        // [NPACK_BLOCKS * PACK_EPB]
    __half* __restrict__ xh)             // [(NN+2)*KF] fp16 copy + zero sentinel rows
{
    // --- fused cvt: x f32 -> xh fp16 (grid-stride, float2 granules) ---
    {
        const float2* __restrict__ x2 = (const float2*)x;
        half2v* __restrict__ xhw = (half2v*)xh;
        const int n2 = (NN + 2) * (KF / 2);
        for (int i = blockIdx.x * 1024 + threadIdx.x; i < n2; i += NPACK_BLOCKS * 1024) {
            float2 v = (i < NN * (KF / 2)) ? x2[i] : make_float2(0.f, 0.f);
            xhw[i] = (half2v){(_Float16)v.x, (_Float16)v.y};
        }
    }

    __shared__ int cnt[NBKT];            // hist -> becomes cursor
    __shared__ int ps[800];              // pair-compressed scan

    const int t = threadIdx.x;
    for (int i = t; i < NBKT; i += 1024) cnt[i] = 0;
    __syncthreads();

    unsigned pk[8];
    int bk[8];
    const long blockBase = (long)blockIdx.x * PACK_EPB;
#pragma unroll
    for (int j = 0; j < 8; ++j) {
        long e = blockBase + j * 1024 + t;       // coalesced per j
        bk[j] = -1;
        if (e < NEDGE_ALL) {
            int list = e >= NE;
            int ee = (int)(list ? e - NE : e);
            const int* ei = list ? ei_neg : ei_pos;
            int src = ei[ee];
            int dst = ei[NE + ee];
            int b = list * NBKT_PER + (dst >> 7);
            bk[j] = b;
            pk[j] = ((unsigned)(dst & 127) << 17) | (unsigned)src;
            atomicAdd(&cnt[b], 1);               // native int LDS atomic
        }
    }
    __syncthreads();

    // exclusive scan over cnt[1564]: pair-compress to 782, Hillis-Steele, expand
    if (t < 782) ps[t] = cnt[2 * t] + cnt[2 * t + 1];
    __syncthreads();
    for (int d = 1; d < 782; d <<= 1) {
        int v = (t < 782 && t >= d) ? ps[t - d] : 0;
        __syncthreads();
        if (t < 782) ps[t] += v;
        __syncthreads();
    }
    if (t < 782) {
        int base = t ? ps[t - 1] : 0;
        int c0 = cnt[2 * t];
        int o0 = base, o1 = base + c0;
        offT[(2 * t) * OT_STRIDE + blockIdx.x]     = (unsigned short)o0;
        offT[(2 * t + 1) * OT_STRIDE + blockIdx.x] = (unsigned short)o1;
        cnt[2 * t] = o0;
        cnt[2 * t + 1] = o1;
    }
    if (t == 0) offT[NBKT * OT_STRIDE + blockIdx.x] = (unsigned short)ps[781];
    __syncthreads();

    unsigned* myregion = plist + (long)blockIdx.x * PACK_EPB;
#pragma unroll
    for (int j = 0; j < 8; ++j) {
        if (bk[j] >= 0) {
            int slot = atomicAdd(&cnt[bk[j]], 1);    // LDS cursor
            myregion[slot] = pk[j];                  // dense store in private region
        }
    }
}

// -------- phase 2: 2-pass bucket assembly (hist + place) then quad-edge gather -------
// 256 threads, ~12KB LDS -> 8 blocks/CU (wave-capped), single dispatch round.
__global__ __launch_bounds__(256) void gather_kernel(
    const __half* __restrict__ xh,
    const unsigned* __restrict__ plist,
    const unsigned short* __restrict__ offT,
    float* __restrict__ xpos,
    float* __restrict__ xneg)
{
    __shared__ unsigned srt[CAP2];       // 9.5 KB
    __shared__ int nh[BKT_NODES];
    __shared__ int starts[BKT_NODES];
    __shared__ int ends[BKT_NODES];
    __shared__ int cur2[BKT_NODES];

    const int b = blockIdx.x;
    const int t = threadIdx.x;

    if (t < BKT_NODES) nh[t] = 0;
    __syncthreads();

    // pass 1: histogram destinations over this bucket's runs
    for (int r = t; r < NPACK_BLOCKS; r += 256) {
        int s = offT[b * OT_STRIDE + r];
        int e = offT[(b + 1) * OT_STRIDE + r];
        const unsigned* p = plist + (long)r * PACK_EPB;
        for (int k = s; k < e; ++k) atomicAdd(&nh[p[k] >> 17], 1);
    }
    __syncthreads();

    // inclusive scan over nh[128]
    for (int d = 1; d < BKT_NODES; d <<= 1) {
        int v = 0;
        if (t < BKT_NODES && t >= d) v = nh[t - d];
        __syncthreads();
        if (t < BKT_NODES) nh[t] += v;
        __syncthreads();
    }
    if (t < BKT_NODES) {
        int e_ = min(nh[t], CAP2);
        int s_ = t ? min(nh[t - 1], CAP2) : 0;
        starts[t] = s_;
        ends[t] = e_;
        cur2[t] = s_;
    }
    __syncthreads();

    // pass 2: place edges into per-node segments
    for (int r = t; r < NPACK_BLOCKS; r += 256) {
        int s = offT[b * OT_STRIDE + r];
        int e = offT[(b + 1) * OT_STRIDE + r];
        const unsigned* p = plist + (long)r * PACK_EPB;
        for (int k = s; k < e; ++k) {
            unsigned pk = p[k];
            int slot = atomicAdd(&cur2[pk >> 17], 1);
            if (slot < CAP2) srt[slot] = pk;
        }
    }
    __syncthreads();

    // quad-edge gather: quarter-wave g handles edge j+off+g; lanes sub<12 carry
    // the 96B fp16 row as half4 (8B). 4 independent loads in flight per lane.
    const int wave = t >> 6, lane = t & 63;
    const int g = lane >> 4;                 // 0..3
    const int sub = lane & 15;               // 0..15
    const int subc = (sub < 12) ? sub : 11;  // clamp: dup load, same line
    const int list = b >= NBKT_PER;
    const int nb = list ? b - NBKT_PER : b;
    float* o = list ? xneg : xpos;
    const half4v* __restrict__ xh4 = (const half4v*)xh;

    for (int n = wave * 32; n < wave * 32 + 32; ++n) {
        int gn = nb * BKT_NODES + n;
        if (gn >= NN) break;
        int s = starts[n], e = ends[n];
        float a0 = 0.f, a1 = 0.f, a2 = 0.f, a3 = 0.f;
        for (int j = s; j < e; j += 16) {
            int i0 = j + g, i1 = j + 4 + g, i2 = j + 8 + g, i3 = j + 12 + g;
            int s0 = (i0 < e) ? (int)(srt[i0 < CAP2 ? i0 : 0] & 0x1FFFFu) : NN;
            int s1 = (i1 < e) ? (int)(srt[i1 < CAP2 ? i1 : 0] & 0x1FFFFu) : NN;
            int s2 = (i2 < e) ? (int)(srt[i2 < CAP2 ? i2 : 0] & 0x1FFFFu) : NN;
            int s3 = (i3 < e) ? (int)(srt[i3 < CAP2 ? i3 : 0] & 0x1FFFFu) : NN;
            half4v v0 = xh4[s0 * 12 + subc];
            half4v v1 = xh4[s1 * 12 + subc];
            half4v v2 = xh4[s2 * 12 + subc];
            half4v v3 = xh4[s3 * 12 + subc];
            acc_pair(a0, a1, (half2v){v0.x, v0.y});
            acc_pair(a2, a3, (half2v){v0.z, v0.w});
            acc_pair(a0, a1, (half2v){v1.x, v1.y});
            acc_pair(a2, a3, (half2v){v1.z, v1.w});
            acc_pair(a0, a1, (half2v){v2.x, v2.y});
            acc_pair(a2, a3, (half2v){v2.z, v2.w});
            acc_pair(a0, a1, (half2v){v3.x, v3.y});
            acc_pair(a2, a3, (half2v){v3.z, v3.w});
        }
        // butterfly-combine the 4 quarter-wave partials (xor 16, 32)
        a0 += __shfl_xor(a0, 16); a0 += __shfl_xor(a0, 32);
        a1 += __shfl_xor(a1, 16); a1 += __shfl_xor(a1, 32);
        a2 += __shfl_xor(a2, 16); a2 += __shfl_xor(a2, 32);
        a3 += __shfl_xor(a3, 16); a3 += __shfl_xor(a3, 32);
        if (g == 0 && sub < 12) {
            float4* o4 = (float4*)o;
            o4[(long)gn * 12 + sub] = make_float4(a0, a1, a2, a3);
        }
    }
}

// ============== fallback scatter (if ws too small) ==============
__global__ __launch_bounds__(256) void scatter2_kernel(
    const float* __restrict__ x,
    const int* __restrict__ ei_pos,
    const int* __restrict__ ei_neg,
    float* acc_pos,
    float* acc_neg)
{
    const int list = blockIdx.y;
    const int* ei = list ? ei_neg : ei_pos;
    float* acc = list ? acc_neg : acc_pos;

    long t = (long)blockIdx.x * blockDim.x + threadIdx.x;
    const long total = (long)NE * 12;
    if (t >= total) return;

    int e = (int)(t / 12);
    int r = (int)(t - (long)e * 12);
    int k4 = r * 4;

    int src = ei[e];
    int dst = ei[NE + e];

    const float4 v = *(const float4*)(x + (long)src * KF + k4);
    float* p = acc + (long)dst * KF + k4;

    unsafeAtomicAdd(p + 0, v.x);
    unsafeAtomicAdd(p + 1, v.y);
    unsafeAtomicAdd(p + 2, v.z);
    unsafeAtomicAdd(p + 3, v.w);
}

// ---------------- fused MLP (tanh) + linear + softmax: 1 thread per node -----------
// NOTE: xpos aliases out. Each thread reads its own row fully before writing it.
__global__ __launch_bounds__(256) void mlp_softmax_kernel(
    const float* __restrict__ x,
    const float* xpos,
    const float* __restrict__ xneg,
    const float* __restrict__ W1,   // [144,16]
    const float* __restrict__ b1,
    const float* __restrict__ W2,   // [16,48]
    const float* __restrict__ b2,
    float* out)
{
    __shared__ float sW1[144 * 16];
    __shared__ float sW2[16 * 48];
    __shared__ float sb1[16];
    __shared__ float sb2[48];

    for (int i = threadIdx.x; i < 144 * 16; i += blockDim.x) sW1[i] = W1[i];
    for (int i = threadIdx.x; i < 16 * 48;  i += blockDim.x) sW2[i] = W2[i];
    if (threadIdx.x < 16) sb1[threadIdx.x] = b1[threadIdx.x];
    if (threadIdx.x < 48) sb2[threadIdx.x] = b2[threadIdx.x];
    __syncthreads();

    const int n = blockIdx.x * blockDim.x + threadIdx.x;
    if (n >= NN) return;

    float h[16];
#pragma unroll
    for (int j = 0; j < 16; ++j) h[j] = sb1[j];

    const float* srcs[3];
    srcs[0] = x    + (long)n * KF;
    srcs[1] = xpos + (long)n * KF;
    srcs[2] = xneg + (long)n * KF;

    for (int s = 0; s < 3; ++s) {
        const float* px = srcs[s];
        for (int i = 0; i < KF; ++i) {
            const float v = px[i];
            const float* w = &sW1[(s * KF + i) * 16];
#pragma unroll
            for (int j = 0; j < 16; ++j) h[j] += v * w[j];
        }
    }
#pragma unroll
    for (int j = 0; j < 16; ++j) h[j] = tanhf(h[j]);

    float C[KF];
#pragma unroll
    for (int k = 0; k < KF; ++k) C[k] = sb2[k];
    for (int j = 0; j < 16; ++j) {
        const float hv = h[j];
        const float* w = &sW2[j * KF];
#pragma unroll
        for (int k = 0; k < KF; ++k) C[k] += hv * w[k];
    }

    float m = C[0];
#pragma unroll
    for (int k = 1; k < KF; ++k) m = fmaxf(m, C[k]);
    float ssum = 0.f;
#pragma unroll
    for (int k = 0; k < KF; ++k) { C[k] = expf(C[k] - m); ssum += C[k]; }
    const float inv = 1.0f / ssum;

    float* po = out + (long)n * KF;
#pragma unroll
    for (int k = 0; k < KF; ++k) po[k] = C[k] * inv;
}

extern "C" void kernel_launch(void* const* d_in, const int* in_sizes, int n_in,
                              void* d_out, int out_size, void* d_ws, size_t ws_size,
                              hipStream_t stream)
{
    const float* x      = (const float*)d_in[0];
    const int*   ei_pos = (const int*)  d_in[1];
    const int*   ei_neg = (const int*)  d_in[2];
    const float* W1     = (const float*)d_in[3];
    const float* b1     = (const float*)d_in[4];
    const float* W2     = (const float*)d_in[5];
    const float* b2     = (const float*)d_in[6];

    float* out  = (float*)d_out;
    float* xpos = (float*)d_out;                 // x_pos accumulator aliases out

    const size_t acc_bytes   = (size_t)NN * KF * sizeof(float);                  // 19.2 MB
    const size_t plist_bytes = (size_t)NPACK_BLOCKS * PACK_EPB * sizeof(unsigned); // 12.8 MB
    const size_t offT_bytes  = (size_t)(NBKT + 1) * OT_STRIDE * sizeof(unsigned short); // 1.23 MB
    const size_t xh_bytes    = (size_t)(NN + 2) * KF * sizeof(__half);           // 9.6 MB

    // ws layout: [xneg | plist | offT | xh]
    size_t off = 0;
    char* ws = (char*)d_ws;
    float*          xneg  = (float*)(ws + off);          off += acc_bytes;
    unsigned*       plist = (unsigned*)(ws + off);       off += plist_bytes;
    unsigned short* offT  = (unsigned short*)(ws + off); off += offT_bytes;
    __half*         xh    = (__half*)(ws + off);         off += xh_bytes;
    const size_t needed = off;

    if (ws_size >= needed) {
        pack_kernel<<<NPACK_BLOCKS, 1024, 0, stream>>>(x, ei_pos, ei_neg, offT, plist, xh);
        gather_kernel<<<NBKT, 256, 0, stream>>>(xh, plist, offT, xpos, xneg);
    } else {
        // fallback: atomic scatter
        hipMemsetAsync(xpos, 0, acc_bytes, stream);
        hipMemsetAsync(xneg, 0, acc_bytes, stream);
        const long total = (long)NE * 12;
        dim3 grid((unsigned)((total + 255) / 256), 2, 1);
        scatter2_kernel<<<grid, 256, 0, stream>>>(x, ei_pos, ei_neg, xpos, xneg);
    }

    mlp_softmax_kernel<<<(NN + 255) / 256, 256, 0, stream>>>(x, xpos, xneg, W1, b1, W2, b2, out);
}

// Round 9
// 257.694 us; speedup vs baseline: 1.1083x; 1.1083x over previous
//
#include <hip/hip_runtime.h>
#include <hip/hip_fp16.h>
#include <math.h>

#define NN 100000
#define NE 1600000
#define KF 48
#define NEDGE_ALL (2 * NE)

#define BKT_NODES 128                    // nodes per bucket (dst >> 7)
#define NBKT_PER  782                    // ceil(100000/128)
#define NBKT      1564                   // pos buckets then neg buckets
#define PACK_EPB  8192                   // edges per pack block (private region size)
#define NPACK_BLOCKS 391                 // ceil(3.2M / 8192)
#define OT_STRIDE 392                    // offT row stride (>= NPACK_BLOCKS)
#define CAP2      2432                   // per-bucket srt capacity (mean 2046 + >8 sigma)
#define GT        384                    // gather threads (6 waves)

typedef _Float16 half2v __attribute__((ext_vector_type(2)));
typedef _Float16 half4v __attribute__((ext_vector_type(4)));

#if defined(__has_builtin)
#if __has_builtin(__builtin_amdgcn_fdot2)
#define HAVE_FDOT2 1
#endif
#endif

__device__ __forceinline__ void acc_pair(float& ax, float& ay, half2v v)
{
#ifdef HAVE_FDOT2
    ax = __builtin_amdgcn_fdot2(v, (half2v){(_Float16)1.f, (_Float16)0.f}, ax, false);
    ay = __builtin_amdgcn_fdot2(v, (half2v){(_Float16)0.f, (_Float16)1.f}, ay, false);
#else
    ax += (float)v.x;
    ay += (float)v.y;
#endif
}

// ---------------- phase 1: fused cvt + atomic-free block-private pack ----------------
// UNCHANGED from round 8 (isolate the gather change; pack becomes top dispatch
// next profile so we finally get its counters).
__global__ __launch_bounds__(1024) void pack_kernel(
    const float* __restrict__ x,
    const int* __restrict__ ei_pos,
    const int* __restrict__ ei_neg,
    unsigned short* __restrict__ offT,   // [(NBKT+1) * OT_STRIDE]
    unsigned* __restrict__ plist,        // [NPACK_BLOCKS * PACK_EPB]
    __half* __restrict__ xh)             // [(NN+2)*KF] fp16 copy + zero sentinel rows
{
    // --- fused cvt: x f32 -> xh fp16 (grid-stride, float2 granules) ---
    {
        const float2* __restrict__ x2 = (const float2*)x;
        half2v* __restrict__ xhw = (half2v*)xh;
        const int n2 = (NN + 2) * (KF / 2);
        for (int i = blockIdx.x * 1024 + threadIdx.x; i < n2; i += NPACK_BLOCKS * 1024) {
            float2 v = (i < NN * (KF / 2)) ? x2[i] : make_float2(0.f, 0.f);
            xhw[i] = (half2v){(_Float16)v.x, (_Float16)v.y};
        }
    }

    __shared__ int cnt[NBKT];            // hist -> becomes cursor
    __shared__ int ps[800];              // pair-compressed scan

    const int t = threadIdx.x;
    for (int i = t; i < NBKT; i += 1024) cnt[i] = 0;
    __syncthreads();

    unsigned pk[8];
    int bk[8];
    const long blockBase = (long)blockIdx.x * PACK_EPB;
#pragma unroll
    for (int j = 0; j < 8; ++j) {
        long e = blockBase + j * 1024 + t;       // coalesced per j
        bk[j] = -1;
        if (e < NEDGE_ALL) {
            int list = e >= NE;
            int ee = (int)(list ? e - NE : e);
            const int* ei = list ? ei_neg : ei_pos;
            int src = ei[ee];
            int dst = ei[NE + ee];
            int b = list * NBKT_PER + (dst >> 7);
            bk[j] = b;
            pk[j] = ((unsigned)(dst & 127) << 17) | (unsigned)src;
            atomicAdd(&cnt[b], 1);               // native int LDS atomic
        }
    }
    __syncthreads();

    // exclusive scan over cnt[1564]: pair-compress to 782, Hillis-Steele, expand
    if (t < 782) ps[t] = cnt[2 * t] + cnt[2 * t + 1];
    __syncthreads();
    for (int d = 1; d < 782; d <<= 1) {
        int v = (t < 782 && t >= d) ? ps[t - d] : 0;
        __syncthreads();
        if (t < 782) ps[t] += v;
        __syncthreads();
    }
    if (t < 782) {
        int base = t ? ps[t - 1] : 0;
        int c0 = cnt[2 * t];
        int o0 = base, o1 = base + c0;
        offT[(2 * t) * OT_STRIDE + blockIdx.x]     = (unsigned short)o0;
        offT[(2 * t + 1) * OT_STRIDE + blockIdx.x] = (unsigned short)o1;
        cnt[2 * t] = o0;
        cnt[2 * t + 1] = o1;
    }
    if (t == 0) offT[NBKT * OT_STRIDE + blockIdx.x] = (unsigned short)ps[781];
    __syncthreads();

    unsigned* myregion = plist + (long)blockIdx.x * PACK_EPB;
#pragma unroll
    for (int j = 0; j < 8; ++j) {
        if (bk[j] >= 0) {
            int slot = atomicAdd(&cnt[bk[j]], 1);    // LDS cursor
            myregion[slot] = pk[j];                  // dense store in private region
        }
    }
}

// -------- phase 2: single-pass staging + LDS sort + quad-edge gather -------
// 384 threads, ~26KB LDS -> 5 blocks/CU (30 waves, ~94% occupancy).
__global__ __launch_bounds__(GT) void gather_kernel(
    const __half* __restrict__ xh,
    const unsigned* __restrict__ plist,
    const unsigned short* __restrict__ offT,
    float* __restrict__ xpos,
    float* __restrict__ xneg)
{
    __shared__ unsigned raw[CAP2];       // 9.5 KB
    __shared__ unsigned srt[CAP2];       // 9.5 KB
    __shared__ int rl[NPACK_BLOCKS];     // run lengths
    __shared__ int rs[NPACK_BLOCKS];     // run source starts
    __shared__ int rb[NPACK_BLOCKS];     // run dest bases
    __shared__ int ps[200];              // pair-compressed run scan
    __shared__ int nh[BKT_NODES];
    __shared__ int starts[BKT_NODES];
    __shared__ int ends[BKT_NODES];
    __shared__ int cur2[BKT_NODES];

    const int b = blockIdx.x;
    const int t = threadIdx.x;

    // run table for bucket b (runs 384..390 handled by threads 0..6 second pass)
    for (int r = t; r < NPACK_BLOCKS; r += GT) {
        int s = offT[b * OT_STRIDE + r];
        int e = offT[(b + 1) * OT_STRIDE + r];
        rl[r] = e - s;
        rs[r] = s;
    }
    __syncthreads();

    // exclusive run-base scan: pair-compress 391 -> 196, H-S scan, expand
    if (t < 196) {
        int a = rl[2 * t];
        int b2 = (2 * t + 1 < NPACK_BLOCKS) ? rl[2 * t + 1] : 0;
        ps[t] = a + b2;
    }
    __syncthreads();
    for (int d = 1; d < 196; d <<= 1) {
        int v = (t < 196 && t >= d) ? ps[t - d] : 0;
        __syncthreads();
        if (t < 196) ps[t] += v;
        __syncthreads();
    }
    if (t < 196) {
        int base = t ? ps[t - 1] : 0;
        rb[2 * t] = base;
        if (2 * t + 1 < NPACK_BLOCKS) rb[2 * t + 1] = base + rl[2 * t];
    }
    if (t < BKT_NODES) nh[t] = 0;
    __syncthreads();
    int cb = ps[195];
    if (cb > CAP2) cb = CAP2;

    // single-pass staging: copy each run into raw
    for (int r = t; r < NPACK_BLOCKS; r += GT) {
        int len = rl[r];
        int dst = rb[r];
        const unsigned* srcp = plist + (long)r * PACK_EPB + rs[r];
        for (int k = 0; k < len; ++k) {
            int d2 = dst + k;
            if (d2 < CAP2) raw[d2] = srcp[k];
        }
    }
    __syncthreads();

    // histogram destinations
    for (int i = t; i < cb; i += GT) atomicAdd(&nh[raw[i] >> 17], 1);
    __syncthreads();
    for (int d = 1; d < BKT_NODES; d <<= 1) {
        int v = 0;
        if (t < BKT_NODES && t >= d) v = nh[t - d];
        __syncthreads();
        if (t < BKT_NODES) nh[t] += v;
        __syncthreads();
    }
    if (t < BKT_NODES) {
        int e_ = min(nh[t], CAP2);
        int s_ = t ? min(nh[t - 1], CAP2) : 0;
        starts[t] = s_;
        ends[t] = e_;
        cur2[t] = s_;
    }
    __syncthreads();

    // place into per-node segments
    for (int i = t; i < cb; i += GT) {
        unsigned p = raw[i];
        int slot = atomicAdd(&cur2[p >> 17], 1);
        if (slot < CAP2) srt[slot] = p;
    }
    __syncthreads();

    // quad-edge gather: quarter-wave g handles edges j+g, j+4+g, j+8+g, j+12+g;
    // lanes sub<12 carry the 96B fp16 row as half4. 4 loads in flight per lane.
    const int wave = t >> 6, lane = t & 63;
    const int g = lane >> 4;                 // 0..3
    const int sub = lane & 15;               // 0..15
    const int subc = (sub < 12) ? sub : 11;  // clamp: dup load, same line
    const int list = b >= NBKT_PER;
    const int nb = list ? b - NBKT_PER : b;
    float* o = list ? xneg : xpos;
    const half4v* __restrict__ xh4 = (const half4v*)xh;

    for (int n = wave; n < BKT_NODES; n += 6) {
        int gn = nb * BKT_NODES + n;
        if (gn >= NN) continue;
        int s = starts[n], e = ends[n];
        float a0 = 0.f, a1 = 0.f, a2 = 0.f, a3 = 0.f;
        for (int j = s; j < e; j += 16) {
            int i0 = j + g, i1 = j + 4 + g, i2 = j + 8 + g, i3 = j + 12 + g;
            int s0 = (i0 < e) ? (int)(srt[i0 < CAP2 ? i0 : 0] & 0x1FFFFu) : NN;
            int s1 = (i1 < e) ? (int)(srt[i1 < CAP2 ? i1 : 0] & 0x1FFFFu) : NN;
            int s2 = (i2 < e) ? (int)(srt[i2 < CAP2 ? i2 : 0] & 0x1FFFFu) : NN;
            int s3 = (i3 < e) ? (int)(srt[i3 < CAP2 ? i3 : 0] & 0x1FFFFu) : NN;
            half4v v0 = xh4[s0 * 12 + subc];
            half4v v1 = xh4[s1 * 12 + subc];
            half4v v2 = xh4[s2 * 12 + subc];
            half4v v3 = xh4[s3 * 12 + subc];
            acc_pair(a0, a1, (half2v){v0.x, v0.y});
            acc_pair(a2, a3, (half2v){v0.z, v0.w});
            acc_pair(a0, a1, (half2v){v1.x, v1.y});
            acc_pair(a2, a3, (half2v){v1.z, v1.w});
            acc_pair(a0, a1, (half2v){v2.x, v2.y});
            acc_pair(a2, a3, (half2v){v2.z, v2.w});
            acc_pair(a0, a1, (half2v){v3.x, v3.y});
            acc_pair(a2, a3, (half2v){v3.z, v3.w});
        }
        // butterfly-combine the 4 quarter-wave partials (xor 16, 32)
        a0 += __shfl_xor(a0, 16); a0 += __shfl_xor(a0, 32);
        a1 += __shfl_xor(a1, 16); a1 += __shfl_xor(a1, 32);
        a2 += __shfl_xor(a2, 16); a2 += __shfl_xor(a2, 32);
        a3 += __shfl_xor(a3, 16); a3 += __shfl_xor(a3, 32);
        if (g == 0 && sub < 12) {
            float4* o4 = (float4*)o;
            o4[(long)gn * 12 + sub] = make_float4(a0, a1, a2, a3);
        }
    }
}

// ============== fallback scatter (if ws too small) ==============
__global__ __launch_bounds__(256) void scatter2_kernel(
    const float* __restrict__ x,
    const int* __restrict__ ei_pos,
    const int* __restrict__ ei_neg,
    float* acc_pos,
    float* acc_neg)
{
    const int list = blockIdx.y;
    const int* ei = list ? ei_neg : ei_pos;
    float* acc = list ? acc_neg : acc_pos;

    long t = (long)blockIdx.x * blockDim.x + threadIdx.x;
    const long total = (long)NE * 12;
    if (t >= total) return;

    int e = (int)(t / 12);
    int r = (int)(t - (long)e * 12);
    int k4 = r * 4;

    int src = ei[e];
    int dst = ei[NE + e];

    const float4 v = *(const float4*)(x + (long)src * KF + k4);
    float* p = acc + (long)dst * KF + k4;

    unsafeAtomicAdd(p + 0, v.x);
    unsafeAtomicAdd(p + 1, v.y);
    unsafeAtomicAdd(p + 2, v.z);
    unsafeAtomicAdd(p + 3, v.w);
}

// ---------------- fused MLP (tanh) + linear + softmax: 1 thread per node -----------
// NOTE: xpos aliases out. Each thread reads its own row fully before writing it.
__global__ __launch_bounds__(256) void mlp_softmax_kernel(
    const float* __restrict__ x,
    const float* xpos,
    const float* __restrict__ xneg,
    const float* __restrict__ W1,   // [144,16]
    const float* __restrict__ b1,
    const float* __restrict__ W2,   // [16,48]
    const float* __restrict__ b2,
    float* out)
{
    __shared__ float sW1[144 * 16];
    __shared__ float sW2[16 * 48];
    __shared__ float sb1[16];
    __shared__ float sb2[48];

    for (int i = threadIdx.x; i < 144 * 16; i += blockDim.x) sW1[i] = W1[i];
    for (int i = threadIdx.x; i < 16 * 48;  i += blockDim.x) sW2[i] = W2[i];
    if (threadIdx.x < 16) sb1[threadIdx.x] = b1[threadIdx.x];
    if (threadIdx.x < 48) sb2[threadIdx.x] = b2[threadIdx.x];
    __syncthreads();

    const int n = blockIdx.x * blockDim.x + threadIdx.x;
    if (n >= NN) return;

    float h[16];
#pragma unroll
    for (int j = 0; j < 16; ++j) h[j] = sb1[j];

    const float* srcs[3];
    srcs[0] = x    + (long)n * KF;
    srcs[1] = xpos + (long)n * KF;
    srcs[2] = xneg + (long)n * KF;

    for (int s = 0; s < 3; ++s) {
        const float* px = srcs[s];
        for (int i = 0; i < KF; ++i) {
            const float v = px[i];
            const float* w = &sW1[(s * KF + i) * 16];
#pragma unroll
            for (int j = 0; j < 16; ++j) h[j] += v * w[j];
        }
    }
#pragma unroll
    for (int j = 0; j < 16; ++j) h[j] = tanhf(h[j]);

    float C[KF];
#pragma unroll
    for (int k = 0; k < KF; ++k) C[k] = sb2[k];
    for (int j = 0; j < 16; ++j) {
        const float hv = h[j];
        const float* w = &sW2[j * KF];
#pragma unroll
        for (int k = 0; k < KF; ++k) C[k] += hv * w[k];
    }

    float m = C[0];
#pragma unroll
    for (int k = 1; k < KF; ++k) m = fmaxf(m, C[k]);
    float ssum = 0.f;
#pragma unroll
    for (int k = 0; k < KF; ++k) { C[k] = expf(C[k] - m); ssum += C[k]; }
    const float inv = 1.0f / ssum;

    float* po = out + (long)n * KF;
#pragma unroll
    for (int k = 0; k < KF; ++k) po[k] = C[k] * inv;
}

extern "C" void kernel_launch(void* const* d_in, const int* in_sizes, int n_in,
                              void* d_out, int out_size, void* d_ws, size_t ws_size,
                              hipStream_t stream)
{
    const float* x      = (const float*)d_in[0];
    const int*   ei_pos = (const int*)  d_in[1];
    const int*   ei_neg = (const int*)  d_in[2];
    const float* W1     = (const float*)d_in[3];
    const float* b1     = (const float*)d_in[4];
    const float* W2     = (const float*)d_in[5];
    const float* b2     = (const float*)d_in[6];

    float* out  = (float*)d_out;
    float* xpos = (float*)d_out;                 // x_pos accumulator aliases out

    const size_t acc_bytes   = (size_t)NN * KF * sizeof(float);                  // 19.2 MB
    const size_t plist_bytes = (size_t)NPACK_BLOCKS * PACK_EPB * sizeof(unsigned); // 12.8 MB
    const size_t offT_bytes  = (size_t)(NBKT + 1) * OT_STRIDE * sizeof(unsigned short); // 1.23 MB
    const size_t xh_bytes    = (size_t)(NN + 2) * KF * sizeof(__half);           // 9.6 MB

    // ws layout: [xneg | plist | offT | xh]
    size_t off = 0;
    char* ws = (char*)d_ws;
    float*          xneg  = (float*)(ws + off);          off += acc_bytes;
    unsigned*       plist = (unsigned*)(ws + off);       off += plist_bytes;
    unsigned short* offT  = (unsigned short*)(ws + off); off += offT_bytes;
    __half*         xh    = (__half*)(ws + off);         off += xh_bytes;
    const size_t needed = off;

    if (ws_size >= needed) {
        pack_kernel<<<NPACK_BLOCKS, 1024, 0, stream>>>(x, ei_pos, ei_neg, offT, plist, xh);
        gather_kernel<<<NBKT, GT, 0, stream>>>(xh, plist, offT, xpos, xneg);
    } else {
        // fallback: atomic scatter
        hipMemsetAsync(xpos, 0, acc_bytes, stream);
        hipMemsetAsync(xneg, 0, acc_bytes, stream);
        const long total = (long)NE * 12;
        dim3 grid((unsigned)((total + 255) / 256), 2, 1);
        scatter2_kernel<<<grid, 256, 0, stream>>>(x, ei_pos, ei_neg, xpos, xneg);
    }

    mlp_softmax_kernel<<<(NN + 255) / 256, 256, 0, stream>>>(x, xpos, xneg, W1, b1, W2, b2, out);
}

// Round 10
// 243.817 us; speedup vs baseline: 1.1714x; 1.0569x over previous
//
#include <hip/hip_runtime.h>
#include <hip/hip_fp16.h>
#include <math.h>

#define NN 100000
#define NE 1600000
#define KF 48
#define NEDGE_ALL (2 * NE)

#define BKT_NODES 128                    // nodes per bucket (dst >> 7)
#define NBKT_PER  782                    // ceil(100000/128)
#define NBKT      1564                   // pos buckets then neg buckets
#define PACK_EPB  4096                   // edges per pack block (private region size)
#define NPB       782                    // pack blocks = ceil(3.2M / 4096)
#define OT2       1566                   // offT_T row stride (>= NBKT+1, even)
#define CAP2      2432                   // per-bucket srt capacity (mean 2046 + >8 sigma)
#define KSTG      10                     // staging registers per thread (10*256 >= CAP2)

typedef _Float16 half2v __attribute__((ext_vector_type(2)));
typedef _Float16 half4v __attribute__((ext_vector_type(4)));

#if defined(__has_builtin)
#if __has_builtin(__builtin_amdgcn_fdot2)
#define HAVE_FDOT2 1
#endif
#endif

__device__ __forceinline__ void acc_pair(float& ax, float& ay, half2v v)
{
#ifdef HAVE_FDOT2
    ax = __builtin_amdgcn_fdot2(v, (half2v){(_Float16)1.f, (_Float16)0.f}, ax, false);
    ay = __builtin_amdgcn_fdot2(v, (half2v){(_Float16)0.f, (_Float16)1.f}, ay, false);
#else
    ax += (float)v.x;
    ay += (float)v.y;
#endif
}

// ---------------- phase 1: fused cvt + atomic-free block-private pack ----------------
// 782 blocks x 512 threads (8 waves): 4 blocks/CU wave-capped, 1024 slots >= 782
// -> ALL blocks co-resident (round-9's 391x16-wave shape stranded half the CUs
// with 2 serialized blocks). offT is TRANSPOSED: each block writes its own
// 3.1KB contiguous row (round-9 wrote 1565 strided u16 column entries -> 2B RMW
// on cross-XCD-shared lines).
__global__ __launch_bounds__(512) void pack_kernel(
    const float* __restrict__ x,
    const int* __restrict__ ei_pos,
    const int* __restrict__ ei_neg,
    unsigned short* __restrict__ offT,   // [NPB * OT2], row r = pack-block r's bucket starts
    unsigned* __restrict__ plist,        // [NPB * PACK_EPB]
    __half* __restrict__ xh)             // [(NN+2)*KF] fp16 copy + zero sentinel rows
{
    // --- fused cvt: x f32 -> xh fp16 (grid-stride, float2 granules) ---
    {
        const float2* __restrict__ x2 = (const float2*)x;
        half2v* __restrict__ xhw = (half2v*)xh;
        const int n2 = (NN + 2) * (KF / 2);
        for (int i = blockIdx.x * 512 + threadIdx.x; i < n2; i += NPB * 512) {
            float2 v = (i < NN * (KF / 2)) ? x2[i] : make_float2(0.f, 0.f);
            xhw[i] = (half2v){(_Float16)v.x, (_Float16)v.y};
        }
    }

    __shared__ int cnt[NBKT];            // hist -> becomes cursor
    __shared__ int ps[391];              // 4-compressed scan

    const int t = threadIdx.x;
    for (int i = t; i < NBKT; i += 512) cnt[i] = 0;
    __syncthreads();

    unsigned pk[8];
    int bk[8];
    const int blockBase = blockIdx.x * PACK_EPB;
#pragma unroll
    for (int j = 0; j < 8; ++j) {
        int e = blockBase + j * 512 + t;         // coalesced per j
        bk[j] = -1;
        if (e < NEDGE_ALL) {
            int list = e >= NE;
            int ee = list ? e - NE : e;
            const int* ei = list ? ei_neg : ei_pos;
            int src = ei[ee];
            int dst = ei[NE + ee];
            int b = list * NBKT_PER + (dst >> 7);
            bk[j] = b;
            pk[j] = ((unsigned)(dst & 127) << 17) | (unsigned)src;
            atomicAdd(&cnt[b], 1);               // native int LDS atomic
        }
    }
    __syncthreads();

    // exclusive scan over cnt[1564]: 4-compress to 391, H-S, expand
    int s0 = 0, s1 = 0, s2 = 0, s3 = 0;
    if (t < 391) {
        s0 = cnt[4 * t]; s1 = cnt[4 * t + 1]; s2 = cnt[4 * t + 2]; s3 = cnt[4 * t + 3];
        ps[t] = s0 + s1 + s2 + s3;
    }
    __syncthreads();
    for (int d = 1; d < 391; d <<= 1) {
        int v = (t < 391 && t >= d) ? ps[t - d] : 0;
        __syncthreads();
        if (t < 391) ps[t] += v;
        __syncthreads();
    }
    unsigned short* myrow = offT + (long)blockIdx.x * OT2;
    if (t < 391) {
        int base = t ? ps[t - 1] : 0;
        int o0 = base, o1 = o0 + s0, o2 = o1 + s1, o3 = o2 + s2;
        myrow[4 * t]     = (unsigned short)o0;
        myrow[4 * t + 1] = (unsigned short)o1;
        myrow[4 * t + 2] = (unsigned short)o2;
        myrow[4 * t + 3] = (unsigned short)o3;
        cnt[4 * t] = o0; cnt[4 * t + 1] = o1; cnt[4 * t + 2] = o2; cnt[4 * t + 3] = o3;
    }
    if (t == 390) myrow[NBKT] = (unsigned short)ps[390];   // total (= end of bucket 1563)
    __syncthreads();

    unsigned* myregion = plist + (long)blockIdx.x * PACK_EPB;
#pragma unroll
    for (int j = 0; j < 8; ++j) {
        if (bk[j] >= 0) {
            int slot = atomicAdd(&cnt[bk[j]], 1);    // LDS cursor
            myregion[slot] = pk[j];                  // dense store in private region
        }
    }
}

// -------- phase 2: register staging (binsearch) + LDS sort + quad-edge gather -------
// 256 threads, ~17KB LDS -> 8 blocks/CU -> all 1564 blocks co-resident (no tail
// round; round-9's 53% occupancy was the 1280+284 two-round split).
__global__ __launch_bounds__(256) void gather_kernel(
    const __half* __restrict__ xh,
    const unsigned* __restrict__ plist,
    const unsigned short* __restrict__ offT,
    float* __restrict__ xpos,
    float* __restrict__ xneg)
{
    __shared__ unsigned srt[CAP2];       // 9.5 KB (reused as rl[] scratch first)
    __shared__ int rb[NPB + 2];          // 3.1 KB run-base exclusive scan
    __shared__ unsigned short rsL[NPB];  // 1.6 KB run source starts
    __shared__ int tmp[196];             // 0.8 KB 4-compressed scan
    __shared__ int nh[BKT_NODES];
    __shared__ int starts[BKT_NODES];
    __shared__ int ends[BKT_NODES];
    __shared__ int cur2[BKT_NODES];

    const int b = blockIdx.x;
    const int t = threadIdx.x;

    // run table: run r's elements for bucket b = region r, [offT[r][b], offT[r][b+1])
    for (int r = t; r < NPB; r += 256) {
        int s = offT[(long)r * OT2 + b];
        int e = offT[(long)r * OT2 + b + 1];
        rsL[r] = (unsigned short)s;
        srt[r] = (unsigned)(e - s);      // rl scratch
    }
    if (t < BKT_NODES) nh[t] = 0;
    __syncthreads();

    // exclusive run-base scan: 4-compress 782 -> 196, H-S, expand
    int s0 = 0, s1 = 0, s2 = 0, s3 = 0;
    if (t < 196) {
        int i0 = 4 * t;
        s0 = (i0     < NPB) ? (int)srt[i0]     : 0;
        s1 = (i0 + 1 < NPB) ? (int)srt[i0 + 1] : 0;
        s2 = (i0 + 2 < NPB) ? (int)srt[i0 + 2] : 0;
        s3 = (i0 + 3 < NPB) ? (int)srt[i0 + 3] : 0;
        tmp[t] = s0 + s1 + s2 + s3;
    }
    __syncthreads();
    for (int d = 1; d < 196; d <<= 1) {
        int v = (t < 196 && t >= d) ? tmp[t - d] : 0;
        __syncthreads();
        if (t < 196) tmp[t] += v;
        __syncthreads();
    }
    if (t < 196) {
        int base = t ? tmp[t - 1] : 0;
        int i0 = 4 * t;
        if (i0     <= NPB) rb[i0]     = base;
        if (i0 + 1 <= NPB) rb[i0 + 1] = base + s0;
        if (i0 + 2 <= NPB) rb[i0 + 2] = base + s0 + s1;
        if (i0 + 3 <= NPB) rb[i0 + 3] = base + s0 + s1 + s2;
    }
    __syncthreads();
    int cb = rb[NPB];
    if (cb > CAP2) cb = CAP2;

    // staging pass: one coalesced global read per element into REGISTERS,
    // run lookup via 10-step binary search over rb; histogram as we go.
    unsigned held[KSTG];
#pragma unroll
    for (int k = 0; k < KSTG; ++k) {
        int i = t + k * 256;
        held[k] = 0;
        if (i < cb) {
            int lo = 0, hi = NPB - 1;
#pragma unroll
            for (int it = 0; it < 10; ++it) {
                int mid = (lo + hi + 1) >> 1;
                bool ge = (rb[mid] <= i);
                lo = ge ? mid : lo;
                hi = ge ? hi : mid - 1;
            }
            unsigned p = plist[(long)lo * PACK_EPB + rsL[lo] + (i - rb[lo])];
            held[k] = p;
            atomicAdd(&nh[p >> 17], 1);
        }
    }
    __syncthreads();

    // scan node histogram
    for (int d = 1; d < BKT_NODES; d <<= 1) {
        int v = 0;
        if (t < BKT_NODES && t >= d) v = nh[t - d];
        __syncthreads();
        if (t < BKT_NODES) nh[t] += v;
        __syncthreads();
    }
    if (t < BKT_NODES) {
        int e_ = min(nh[t], CAP2);
        int s_ = t ? min(nh[t - 1], CAP2) : 0;
        starts[t] = s_;
        ends[t] = e_;
        cur2[t] = s_;
    }
    __syncthreads();

    // place from registers into per-node segments (overwrites rl scratch - done with it)
#pragma unroll
    for (int k = 0; k < KSTG; ++k) {
        int i = t + k * 256;
        if (i < cb) {
            unsigned p = held[k];
            int slot = atomicAdd(&cur2[p >> 17], 1);
            if (slot < CAP2) srt[slot] = p;
        }
    }
    __syncthreads();

    // quad-edge gather: quarter-wave g handles edges j+g, j+4+g, j+8+g, j+12+g;
    // lanes sub<12 carry the 96B fp16 row as half4. 4 loads in flight per lane.
    const int wave = t >> 6, lane = t & 63;
    const int g = lane >> 4;                 // 0..3
    const int sub = lane & 15;               // 0..15
    const int subc = (sub < 12) ? sub : 11;  // clamp: dup load, same line
    const int list = b >= NBKT_PER;
    const int nb = list ? b - NBKT_PER : b;
    float* o = list ? xneg : xpos;
    const half4v* __restrict__ xh4 = (const half4v*)xh;

    for (int n = wave; n < BKT_NODES; n += 4) {
        int gn = nb * BKT_NODES + n;
        if (gn >= NN) continue;
        int s = starts[n], e = ends[n];
        float a0 = 0.f, a1 = 0.f, a2 = 0.f, a3 = 0.f;
        for (int j = s; j < e; j += 16) {
            int i0 = j + g, i1 = j + 4 + g, i2 = j + 8 + g, i3 = j + 12 + g;
            int q0 = (i0 < e) ? (int)(srt[i0 < CAP2 ? i0 : 0] & 0x1FFFFu) : NN;
            int q1 = (i1 < e) ? (int)(srt[i1 < CAP2 ? i1 : 0] & 0x1FFFFu) : NN;
            int q2 = (i2 < e) ? (int)(srt[i2 < CAP2 ? i2 : 0] & 0x1FFFFu) : NN;
            int q3 = (i3 < e) ? (int)(srt[i3 < CAP2 ? i3 : 0] & 0x1FFFFu) : NN;
            half4v v0 = xh4[q0 * 12 + subc];
            half4v v1 = xh4[q1 * 12 + subc];
            half4v v2 = xh4[q2 * 12 + subc];
            half4v v3 = xh4[q3 * 12 + subc];
            acc_pair(a0, a1, (half2v){v0.x, v0.y});
            acc_pair(a2, a3, (half2v){v0.z, v0.w});
            acc_pair(a0, a1, (half2v){v1.x, v1.y});
            acc_pair(a2, a3, (half2v){v1.z, v1.w});
            acc_pair(a0, a1, (half2v){v2.x, v2.y});
            acc_pair(a2, a3, (half2v){v2.z, v2.w});
            acc_pair(a0, a1, (half2v){v3.x, v3.y});
            acc_pair(a2, a3, (half2v){v3.z, v3.w});
        }
        // butterfly-combine the 4 quarter-wave partials (xor 16, 32)
        a0 += __shfl_xor(a0, 16); a0 += __shfl_xor(a0, 32);
        a1 += __shfl_xor(a1, 16); a1 += __shfl_xor(a1, 32);
        a2 += __shfl_xor(a2, 16); a2 += __shfl_xor(a2, 32);
        a3 += __shfl_xor(a3, 16); a3 += __shfl_xor(a3, 32);
        if (g == 0 && sub < 12) {
            float4* o4 = (float4*)o;
            o4[(long)gn * 12 + sub] = make_float4(a0, a1, a2, a3);
        }
    }
}

// ============== fallback scatter (if ws too small) ==============
__global__ __launch_bounds__(256) void scatter2_kernel(
    const float* __restrict__ x,
    const int* __restrict__ ei_pos,
    const int* __restrict__ ei_neg,
    float* acc_pos,
    float* acc_neg)
{
    const int list = blockIdx.y;
    const int* ei = list ? ei_neg : ei_pos;
    float* acc = list ? acc_neg : acc_pos;

    long t = (long)blockIdx.x * blockDim.x + threadIdx.x;
    const long total = (long)NE * 12;
    if (t >= total) return;

    int e = (int)(t / 12);
    int r = (int)(t - (long)e * 12);
    int k4 = r * 4;

    int src = ei[e];
    int dst = ei[NE + e];

    const float4 v = *(const float4*)(x + (long)src * KF + k4);
    float* p = acc + (long)dst * KF + k4;

    unsafeAtomicAdd(p + 0, v.x);
    unsafeAtomicAdd(p + 1, v.y);
    unsafeAtomicAdd(p + 2, v.z);
    unsafeAtomicAdd(p + 3, v.w);
}

// ---------------- fused MLP (tanh) + linear + softmax: 1 thread per node -----------
// NOTE: xpos aliases out. Each thread reads its own row fully before writing it.
__global__ __launch_bounds__(256) void mlp_softmax_kernel(
    const float* __restrict__ x,
    const float* xpos,
    const float* __restrict__ xneg,
    const float* __restrict__ W1,   // [144,16]
    const float* __restrict__ b1,
    const float* __restrict__ W2,   // [16,48]
    const float* __restrict__ b2,
    float* out)
{
    __shared__ float sW1[144 * 16];
    __shared__ float sW2[16 * 48];
    __shared__ float sb1[16];
    __shared__ float sb2[48];

    for (int i = threadIdx.x; i < 144 * 16; i += blockDim.x) sW1[i] = W1[i];
    for (int i = threadIdx.x; i < 16 * 48;  i += blockDim.x) sW2[i] = W2[i];
    if (threadIdx.x < 16) sb1[threadIdx.x] = b1[threadIdx.x];
    if (threadIdx.x < 48) sb2[threadIdx.x] = b2[threadIdx.x];
    __syncthreads();

    const int n = blockIdx.x * blockDim.x + threadIdx.x;
    if (n >= NN) return;

    float h[16];
#pragma unroll
    for (int j = 0; j < 16; ++j) h[j] = sb1[j];

    const float* srcs[3];
    srcs[0] = x    + (long)n * KF;
    srcs[1] = xpos + (long)n * KF;
    srcs[2] = xneg + (long)n * KF;

    for (int s = 0; s < 3; ++s) {
        const float* px = srcs[s];
        for (int i = 0; i < KF; ++i) {
            const float v = px[i];
            const float* w = &sW1[(s * KF + i) * 16];
#pragma unroll
            for (int j = 0; j < 16; ++j) h[j] += v * w[j];
        }
    }
#pragma unroll
    for (int j = 0; j < 16; ++j) h[j] = tanhf(h[j]);

    float C[KF];
#pragma unroll
    for (int k = 0; k < KF; ++k) C[k] = sb2[k];
    for (int j = 0; j < 16; ++j) {
        const float hv = h[j];
        const float* w = &sW2[j * KF];
#pragma unroll
        for (int k = 0; k < KF; ++k) C[k] += hv * w[k];
    }

    float m = C[0];
#pragma unroll
    for (int k = 1; k < KF; ++k) m = fmaxf(m, C[k]);
    float ssum = 0.f;
#pragma unroll
    for (int k = 0; k < KF; ++k) { C[k] = expf(C[k] - m); ssum += C[k]; }
    const float inv = 1.0f / ssum;

    float* po = out + (long)n * KF;
#pragma unroll
    for (int k = 0; k < KF; ++k) po[k] = C[k] * inv;
}

extern "C" void kernel_launch(void* const* d_in, const int* in_sizes, int n_in,
                              void* d_out, int out_size, void* d_ws, size_t ws_size,
                              hipStream_t stream)
{
    const float* x      = (const float*)d_in[0];
    const int*   ei_pos = (const int*)  d_in[1];
    const int*   ei_neg = (const int*)  d_in[2];
    const float* W1     = (const float*)d_in[3];
    const float* b1     = (const float*)d_in[4];
    const float* W2     = (const float*)d_in[5];
    const float* b2     = (const float*)d_in[6];

    float* out  = (float*)d_out;
    float* xpos = (float*)d_out;                 // x_pos accumulator aliases out

    const size_t acc_bytes   = (size_t)NN * KF * sizeof(float);               // 19.2 MB
    const size_t plist_bytes = (size_t)NPB * PACK_EPB * sizeof(unsigned);     // 12.8 MB
    const size_t offT_bytes  = (size_t)NPB * OT2 * sizeof(unsigned short);    // 2.45 MB
    const size_t xh_bytes    = (size_t)(NN + 2) * KF * sizeof(__half);        // 9.6 MB

    // ws layout: [xneg | plist | offT | xh]
    size_t off = 0;
    char* ws = (char*)d_ws;
    float*          xneg  = (float*)(ws + off);          off += acc_bytes;
    unsigned*       plist = (unsigned*)(ws + off);       off += plist_bytes;
    unsigned short* offT  = (unsigned short*)(ws + off); off += offT_bytes;
    __half*         xh    = (__half*)(ws + off);         off += xh_bytes;
    const size_t needed = off;

    if (ws_size >= needed) {
        pack_kernel<<<NPB, 512, 0, stream>>>(x, ei_pos, ei_neg, offT, plist, xh);
        gather_kernel<<<NBKT, 256, 0, stream>>>(xh, plist, offT, xpos, xneg);
    } else {
        // fallback: atomic scatter
        hipMemsetAsync(xpos, 0, acc_bytes, stream);
        hipMemsetAsync(xneg, 0, acc_bytes, stream);
        const long total = (long)NE * 12;
        dim3 grid((unsigned)((total + 255) / 256), 2, 1);
        scatter2_kernel<<<grid, 256, 0, stream>>>(x, ei_pos, ei_neg, xpos, xneg);
    }

    mlp_softmax_kernel<<<(NN + 255) / 256, 256, 0, stream>>>(x, xpos, xneg, W1, b1, W2, b2, out);
}

// Round 11
// 235.223 us; speedup vs baseline: 1.2142x; 1.0365x over previous
//
#include <hip/hip_runtime.h>
#include <hip/hip_fp16.h>
#include <math.h>

#define NN 100000
#define NE 1600000
#define KF 48
#define NEDGE_ALL (2 * NE)

#define BKT_NODES 128                    // nodes per bucket (dst >> 7)
#define NBKT_PER  782                    // ceil(100000/128)
#define NBKT      1564                   // pos buckets then neg buckets
#define PACK_EPB  4096                   // edges per pack block (private region size)
#define NPB       782                    // pack blocks = ceil(3.2M / 4096)
#define OT2       1566                   // offT row stride (>= NBKT+1, even)
#define CAP2      2432                   // per-bucket srt capacity (mean 2046 + >8 sigma)
#define KSTG      10                     // staging registers per thread (10*256 >= CAP2)

typedef _Float16 half2v __attribute__((ext_vector_type(2)));
typedef _Float16 half4v __attribute__((ext_vector_type(4)));

#if defined(__has_builtin)
#if __has_builtin(__builtin_amdgcn_fdot2)
#define HAVE_FDOT2 1
#endif
#endif

__device__ __forceinline__ void acc_pair(float& ax, float& ay, half2v v)
{
#ifdef HAVE_FDOT2
    ax = __builtin_amdgcn_fdot2(v, (half2v){(_Float16)1.f, (_Float16)0.f}, ax, false);
    ay = __builtin_amdgcn_fdot2(v, (half2v){(_Float16)0.f, (_Float16)1.f}, ay, false);
#else
    ax += (float)v.x;
    ay += (float)v.y;
#endif
}

// ---------------- phase 1: fused cvt + LDS-sorted block-private pack ----------------
// Round-11 change: edges are sorted into a 16KB LDS staging array (scattered
// ds_write ~ cheap), then streamed to the block's global region with COALESCED
// dwordx4 stores. Round-10 scattered 4B global stores fragmented every wave
// store into ~64 transactions (~3.2M total ~= the invariant ~90us pack cost).
__global__ __launch_bounds__(512) void pack_kernel(
    const float* __restrict__ x,
    const int* __restrict__ ei_pos,
    const int* __restrict__ ei_neg,
    unsigned short* __restrict__ offT,   // [NPB * OT2], row r = pack-block r's bucket starts
    unsigned* __restrict__ plist,        // [NPB * PACK_EPB]
    __half* __restrict__ xh)             // [(NN+2)*KF] fp16 copy + zero sentinel rows
{
    // --- fused cvt: x f32 -> xh fp16 (grid-stride, float2 granules) ---
    {
        const float2* __restrict__ x2 = (const float2*)x;
        half2v* __restrict__ xhw = (half2v*)xh;
        const int n2 = (NN + 2) * (KF / 2);
        for (int i = blockIdx.x * 512 + threadIdx.x; i < n2; i += NPB * 512) {
            float2 v = (i < NN * (KF / 2)) ? x2[i] : make_float2(0.f, 0.f);
            xhw[i] = (half2v){(_Float16)v.x, (_Float16)v.y};
        }
    }

    __shared__ int cnt[NBKT];            // hist -> becomes cursor
    __shared__ int ps[391];              // 4-compressed scan
    __shared__ unsigned stage[PACK_EPB]; // 16 KB sorted staging

    const int t = threadIdx.x;
    for (int i = t; i < NBKT; i += 512) cnt[i] = 0;
    __syncthreads();

    unsigned pk[8];
    int bk[8];
    const int blockBase = blockIdx.x * PACK_EPB;
#pragma unroll
    for (int j = 0; j < 8; ++j) {
        int e = blockBase + j * 512 + t;         // coalesced per j
        bk[j] = -1;
        if (e < NEDGE_ALL) {
            int list = e >= NE;
            int ee = list ? e - NE : e;
            const int* ei = list ? ei_neg : ei_pos;
            int src = ei[ee];
            int dst = ei[NE + ee];
            int b = list * NBKT_PER + (dst >> 7);
            bk[j] = b;
            pk[j] = ((unsigned)(dst & 127) << 17) | (unsigned)src;
            atomicAdd(&cnt[b], 1);               // native int LDS atomic
        }
    }
    __syncthreads();

    // exclusive scan over cnt[1564]: 4-compress to 391, H-S, expand
    int s0 = 0, s1 = 0, s2 = 0, s3 = 0;
    if (t < 391) {
        s0 = cnt[4 * t]; s1 = cnt[4 * t + 1]; s2 = cnt[4 * t + 2]; s3 = cnt[4 * t + 3];
        ps[t] = s0 + s1 + s2 + s3;
    }
    __syncthreads();
    for (int d = 1; d < 391; d <<= 1) {
        int v = (t < 391 && t >= d) ? ps[t - d] : 0;
        __syncthreads();
        if (t < 391) ps[t] += v;
        __syncthreads();
    }
    unsigned short* myrow = offT + (long)blockIdx.x * OT2;
    if (t < 391) {
        int base = t ? ps[t - 1] : 0;
        int o0 = base, o1 = o0 + s0, o2 = o1 + s1, o3 = o2 + s2;
        myrow[4 * t]     = (unsigned short)o0;
        myrow[4 * t + 1] = (unsigned short)o1;
        myrow[4 * t + 2] = (unsigned short)o2;
        myrow[4 * t + 3] = (unsigned short)o3;
        cnt[4 * t] = o0; cnt[4 * t + 1] = o1; cnt[4 * t + 2] = o2; cnt[4 * t + 3] = o3;
    }
    if (t == 390) myrow[NBKT] = (unsigned short)ps[390];   // total
    __syncthreads();

    // scatter into LDS staging (cheap), ...
#pragma unroll
    for (int j = 0; j < 8; ++j) {
        if (bk[j] >= 0) {
            int slot = atomicAdd(&cnt[bk[j]], 1);    // LDS cursor
            stage[slot] = pk[j];
        }
    }
    __syncthreads();

    // ... then stream out fully coalesced (uint4 = 16B/lane)
    {
        const uint4* __restrict__ st4 = (const uint4*)stage;
        uint4* __restrict__ out4 = (uint4*)(plist + (long)blockIdx.x * PACK_EPB);
#pragma unroll
        for (int j = 0; j < 2; ++j)
            out4[j * 512 + t] = st4[j * 512 + t];
    }
}

// -------- phase 2: register staging (binsearch) + LDS sort + quad-edge gather -------
// UNCHANGED from round 10 (isolate the pack change).
__global__ __launch_bounds__(256) void gather_kernel(
    const __half* __restrict__ xh,
    const unsigned* __restrict__ plist,
    const unsigned short* __restrict__ offT,
    float* __restrict__ xpos,
    float* __restrict__ xneg)
{
    __shared__ unsigned srt[CAP2];       // 9.5 KB (reused as rl[] scratch first)
    __shared__ int rb[NPB + 2];          // 3.1 KB run-base exclusive scan
    __shared__ unsigned short rsL[NPB];  // 1.6 KB run source starts
    __shared__ int tmp[196];             // 0.8 KB 4-compressed scan
    __shared__ int nh[BKT_NODES];
    __shared__ int starts[BKT_NODES];
    __shared__ int ends[BKT_NODES];
    __shared__ int cur2[BKT_NODES];

    const int b = blockIdx.x;
    const int t = threadIdx.x;

    for (int r = t; r < NPB; r += 256) {
        int s = offT[(long)r * OT2 + b];
        int e = offT[(long)r * OT2 + b + 1];
        rsL[r] = (unsigned short)s;
        srt[r] = (unsigned)(e - s);      // rl scratch
    }
    if (t < BKT_NODES) nh[t] = 0;
    __syncthreads();

    int s0 = 0, s1 = 0, s2 = 0, s3 = 0;
    if (t < 196) {
        int i0 = 4 * t;
        s0 = (i0     < NPB) ? (int)srt[i0]     : 0;
        s1 = (i0 + 1 < NPB) ? (int)srt[i0 + 1] : 0;
        s2 = (i0 + 2 < NPB) ? (int)srt[i0 + 2] : 0;
        s3 = (i0 + 3 < NPB) ? (int)srt[i0 + 3] : 0;
        tmp[t] = s0 + s1 + s2 + s3;
    }
    __syncthreads();
    for (int d = 1; d < 196; d <<= 1) {
        int v = (t < 196 && t >= d) ? tmp[t - d] : 0;
        __syncthreads();
        if (t < 196) tmp[t] += v;
        __syncthreads();
    }
    if (t < 196) {
        int base = t ? tmp[t - 1] : 0;
        int i0 = 4 * t;
        if (i0     <= NPB) rb[i0]     = base;
        if (i0 + 1 <= NPB) rb[i0 + 1] = base + s0;
        if (i0 + 2 <= NPB) rb[i0 + 2] = base + s0 + s1;
        if (i0 + 3 <= NPB) rb[i0 + 3] = base + s0 + s1 + s2;
    }
    __syncthreads();
    int cb = rb[NPB];
    if (cb > CAP2) cb = CAP2;

    unsigned held[KSTG];
#pragma unroll
    for (int k = 0; k < KSTG; ++k) {
        int i = t + k * 256;
        held[k] = 0;
        if (i < cb) {
            int lo = 0, hi = NPB - 1;
#pragma unroll
            for (int it = 0; it < 10; ++it) {
                int mid = (lo + hi + 1) >> 1;
                bool ge = (rb[mid] <= i);
                lo = ge ? mid : lo;
                hi = ge ? hi : mid - 1;
            }
            unsigned p = plist[(long)lo * PACK_EPB + rsL[lo] + (i - rb[lo])];
            held[k] = p;
            atomicAdd(&nh[p >> 17], 1);
        }
    }
    __syncthreads();

    for (int d = 1; d < BKT_NODES; d <<= 1) {
        int v = 0;
        if (t < BKT_NODES && t >= d) v = nh[t - d];
        __syncthreads();
        if (t < BKT_NODES) nh[t] += v;
        __syncthreads();
    }
    if (t < BKT_NODES) {
        int e_ = min(nh[t], CAP2);
        int s_ = t ? min(nh[t - 1], CAP2) : 0;
        starts[t] = s_;
        ends[t] = e_;
        cur2[t] = s_;
    }
    __syncthreads();

#pragma unroll
    for (int k = 0; k < KSTG; ++k) {
        int i = t + k * 256;
        if (i < cb) {
            unsigned p = held[k];
            int slot = atomicAdd(&cur2[p >> 17], 1);
            if (slot < CAP2) srt[slot] = p;
        }
    }
    __syncthreads();

    const int wave = t >> 6, lane = t & 63;
    const int g = lane >> 4;                 // 0..3
    const int sub = lane & 15;               // 0..15
    const int subc = (sub < 12) ? sub : 11;  // clamp: dup load, same line
    const int list = b >= NBKT_PER;
    const int nb = list ? b - NBKT_PER : b;
    float* o = list ? xneg : xpos;
    const half4v* __restrict__ xh4 = (const half4v*)xh;

    for (int n = wave; n < BKT_NODES; n += 4) {
        int gn = nb * BKT_NODES + n;
        if (gn >= NN) continue;
        int s = starts[n], e = ends[n];
        float a0 = 0.f, a1 = 0.f, a2 = 0.f, a3 = 0.f;
        for (int j = s; j < e; j += 16) {
            int i0 = j + g, i1 = j + 4 + g, i2 = j + 8 + g, i3 = j + 12 + g;
            int q0 = (i0 < e) ? (int)(srt[i0 < CAP2 ? i0 : 0] & 0x1FFFFu) : NN;
            int q1 = (i1 < e) ? (int)(srt[i1 < CAP2 ? i1 : 0] & 0x1FFFFu) : NN;
            int q2 = (i2 < e) ? (int)(srt[i2 < CAP2 ? i2 : 0] & 0x1FFFFu) : NN;
            int q3 = (i3 < e) ? (int)(srt[i3 < CAP2 ? i3 : 0] & 0x1FFFFu) : NN;
            half4v v0 = xh4[q0 * 12 + subc];
            half4v v1 = xh4[q1 * 12 + subc];
            half4v v2 = xh4[q2 * 12 + subc];
            half4v v3 = xh4[q3 * 12 + subc];
            acc_pair(a0, a1, (half2v){v0.x, v0.y});
            acc_pair(a2, a3, (half2v){v0.z, v0.w});
            acc_pair(a0, a1, (half2v){v1.x, v1.y});
            acc_pair(a2, a3, (half2v){v1.z, v1.w});
            acc_pair(a0, a1, (half2v){v2.x, v2.y});
            acc_pair(a2, a3, (half2v){v2.z, v2.w});
            acc_pair(a0, a1, (half2v){v3.x, v3.y});
            acc_pair(a2, a3, (half2v){v3.z, v3.w});
        }
        a0 += __shfl_xor(a0, 16); a0 += __shfl_xor(a0, 32);
        a1 += __shfl_xor(a1, 16); a1 += __shfl_xor(a1, 32);
        a2 += __shfl_xor(a2, 16); a2 += __shfl_xor(a2, 32);
        a3 += __shfl_xor(a3, 16); a3 += __shfl_xor(a3, 32);
        if (g == 0 && sub < 12) {
            float4* o4 = (float4*)o;
            o4[(long)gn * 12 + sub] = make_float4(a0, a1, a2, a3);
        }
    }
}

// ============== fallback scatter (if ws too small) ==============
__global__ __launch_bounds__(256) void scatter2_kernel(
    const float* __restrict__ x,
    const int* __restrict__ ei_pos,
    const int* __restrict__ ei_neg,
    float* acc_pos,
    float* acc_neg)
{
    const int list = blockIdx.y;
    const int* ei = list ? ei_neg : ei_pos;
    float* acc = list ? acc_neg : acc_pos;

    long t = (long)blockIdx.x * blockDim.x + threadIdx.x;
    const long total = (long)NE * 12;
    if (t >= total) return;

    int e = (int)(t / 12);
    int r = (int)(t - (long)e * 12);
    int k4 = r * 4;

    int src = ei[e];
    int dst = ei[NE + e];

    const float4 v = *(const float4*)(x + (long)src * KF + k4);
    float* p = acc + (long)dst * KF + k4;

    unsafeAtomicAdd(p + 0, v.x);
    unsafeAtomicAdd(p + 1, v.y);
    unsafeAtomicAdd(p + 2, v.z);
    unsafeAtomicAdd(p + 3, v.w);
}

// ---------------- fused MLP (tanh) + linear + softmax: 1 thread per node -----------
// NOTE: xpos aliases out. Each thread reads its own row fully before writing it.
__global__ __launch_bounds__(256) void mlp_softmax_kernel(
    const float* __restrict__ x,
    const float* xpos,
    const float* __restrict__ xneg,
    const float* __restrict__ W1,   // [144,16]
    const float* __restrict__ b1,
    const float* __restrict__ W2,   // [16,48]
    const float* __restrict__ b2,
    float* out)
{
    __shared__ float sW1[144 * 16];
    __shared__ float sW2[16 * 48];
    __shared__ float sb1[16];
    __shared__ float sb2[48];

    for (int i = threadIdx.x; i < 144 * 16; i += blockDim.x) sW1[i] = W1[i];
    for (int i = threadIdx.x; i < 16 * 48;  i += blockDim.x) sW2[i] = W2[i];
    if (threadIdx.x < 16) sb1[threadIdx.x] = b1[threadIdx.x];
    if (threadIdx.x < 48) sb2[threadIdx.x] = b2[threadIdx.x];
    __syncthreads();

    const int n = blockIdx.x * blockDim.x + threadIdx.x;
    if (n >= NN) return;

    float h[16];
#pragma unroll
    for (int j = 0; j < 16; ++j) h[j] = sb1[j];

    const float* srcs[3];
    srcs[0] = x    + (long)n * KF;
    srcs[1] = xpos + (long)n * KF;
    srcs[2] = xneg + (long)n * KF;

    for (int s = 0; s < 3; ++s) {
        const float* px = srcs[s];
        for (int i = 0; i < KF; ++i) {
            const float v = px[i];
            const float* w = &sW1[(s * KF + i) * 16];
#pragma unroll
            for (int j = 0; j < 16; ++j) h[j] += v * w[j];
        }
    }
#pragma unroll
    for (int j = 0; j < 16; ++j) h[j] = tanhf(h[j]);

    float C[KF];
#pragma unroll
    for (int k = 0; k < KF; ++k) C[k] = sb2[k];
    for (int j = 0; j < 16; ++j) {
        const float hv = h[j];
        const float* w = &sW2[j * KF];
#pragma unroll
        for (int k = 0; k < KF; ++k) C[k] += hv * w[k];
    }

    float m = C[0];
#pragma unroll
    for (int k = 1; k < KF; ++k) m = fmaxf(m, C[k]);
    float ssum = 0.f;
#pragma unroll
    for (int k = 0; k < KF; ++k) { C[k] = expf(C[k] - m); ssum += C[k]; }
    const float inv = 1.0f / ssum;

    float* po = out + (long)n * KF;
#pragma unroll
    for (int k = 0; k < KF; ++k) po[k] = C[k] * inv;
}

extern "C" void kernel_launch(void* const* d_in, const int* in_sizes, int n_in,
                              void* d_out, int out_size, void* d_ws, size_t ws_size,
                              hipStream_t stream)
{
    const float* x      = (const float*)d_in[0];
    const int*   ei_pos = (const int*)  d_in[1];
    const int*   ei_neg = (const int*)  d_in[2];
    const float* W1     = (const float*)d_in[3];
    const float* b1     = (const float*)d_in[4];
    const float* W2     = (const float*)d_in[5];
    const float* b2     = (const float*)d_in[6];

    float* out  = (float*)d_out;
    float* xpos = (float*)d_out;                 // x_pos accumulator aliases out

    const size_t acc_bytes   = (size_t)NN * KF * sizeof(float);               // 19.2 MB
    const size_t plist_bytes = (size_t)NPB * PACK_EPB * sizeof(unsigned);     // 12.8 MB
    const size_t offT_bytes  = (size_t)NPB * OT2 * sizeof(unsigned short);    // 2.45 MB
    const size_t xh_bytes    = (size_t)(NN + 2) * KF * sizeof(__half);        // 9.6 MB

    // ws layout: [xneg | plist | offT | xh]
    size_t off = 0;
    char* ws = (char*)d_ws;
    float*          xneg  = (float*)(ws + off);          off += acc_bytes;
    unsigned*       plist = (unsigned*)(ws + off);       off += plist_bytes;
    unsigned short* offT  = (unsigned short*)(ws + off); off += offT_bytes;
    __half*         xh    = (__half*)(ws + off);         off += xh_bytes;
    const size_t needed = off;

    if (ws_size >= needed) {
        pack_kernel<<<NPB, 512, 0, stream>>>(x, ei_pos, ei_neg, offT, plist, xh);
        gather_kernel<<<NBKT, 256, 0, stream>>>(xh, plist, offT, xpos, xneg);
    } else {
        // fallback: atomic scatter
        hipMemsetAsync(xpos, 0, acc_bytes, stream);
        hipMemsetAsync(xneg, 0, acc_bytes, stream);
        const long total = (long)NE * 12;
        dim3 grid((unsigned)((total + 255) / 256), 2, 1);
        scatter2_kernel<<<grid, 256, 0, stream>>>(x, ei_pos, ei_neg, xpos, xneg);
    }

    mlp_softmax_kernel<<<(NN + 255) / 256, 256, 0, stream>>>(x, xpos, xneg, W1, b1, W2, b2, out);
}